// Round 7
// baseline (52.580 us; speedup 1.0000x reference)
//
#include <hip/hip_runtime.h>
#include <hip/hip_bf16.h>

// JointLengthLoss: mean over [B,20] of | ||pred_a-pred_b|| - ||gt_a-gt_b|| | / ||gt_a-gt_b||
// B = 524288, joints [B,21,3] f32.
//
// R6 = R5 (global_load_lds staging, double-buffered, counted vmcnt) +
//  (a) chain-based joint loads: every bone group expressed as edge(0,1) +
//      chain(2..6) over a 7-joint list -> 42 LDS reads/thread (was 60),
//      compile-time edge indices (no scratch);
//  (b) fused finalization: per-block atomicAdd into d_out[0], 4B memsetAsync
//      at launch head (replay-safe, graph-capturable) -> no 2nd kernel.

#define TILE_BYTES   16128          // 64 samples * 63 floats * 4B
#define TILE_PAD_F   4096           // 16384 B per input per buffer (256B pad for clamped tail)
#define NBLOCKS      512

// 7-joint lists per bone group; edges are ALWAYS (0,1),(2,3),(3,4),(4,5),(5,6).
// g0: bones (3,2),(2,20),(20,8),(8,9),(9,10)      -> {3,2,2,20,8,9,10}
// g1: bones (10,11),(20,4),(4,5),(5,6),(6,7)      -> {10,11,20,4,5,6,7}
// g2: bones (20,1),(1,0),(0,16),(16,17),(17,18)   -> {20,1,1,0,16,17,18}
// g3: bones (18,19),(0,12),(12,13),(13,14),(14,15)-> {18,19,0,12,13,14,15}
static constexpr int JT0[7] = {3,2,2,20,8,9,10};
static constexpr int JT1[7] = {10,11,20,4,5,6,7};
static constexpr int JT2[7] = {20,1,1,0,16,17,18};
static constexpr int JT3[7] = {18,19,0,12,13,14,15};
static constexpr int EA[5] = {0,2,3,4,5};
static constexpr int EB[5] = {1,3,4,5,6};

typedef __attribute__((address_space(1))) const void gvoid_t;
typedef __attribute__((address_space(3))) void lvoid_t;

__global__ __launch_bounds__(256)
void jll_kernel(const float* __restrict__ pred,
                const float* __restrict__ gt,
                float* __restrict__ out,
                float inv_count,
                int tiles_per_block) {
    __shared__ __align__(16) float lds[2][2][TILE_PAD_F];   // [buf][input][floats] = 64 KiB
    __shared__ float wsum[4];

    const int tid  = threadIdx.x;
    const int wave = tid >> 6;
    const int lane = tid & 63;

    // ---- per-thread joint offset table (floats) via branchless selects ----
    const int g = tid & 3;
    int JT[7];
    #pragma unroll
    for (int k = 0; k < 7; ++k) {
        JT[k] = 3 * ((g == 0) ? JT0[k] : (g == 1) ? JT1[k] : (g == 2) ? JT2[k] : JT3[k]);
    }
    const int smoff = (tid >> 2) * 63;        // this thread's sample base (floats) in LDS

    const size_t tile0 = (size_t)blockIdx.x * tiles_per_block;

    // STAGE: 8 global_load_lds per thread (4 chunks x {pred,gt}).
    // LDS dest: wave-uniform base + lane*16 (HW rule). Global src: per-lane.
    // Tail chunk 15: lanes >=48 clamp to the last valid 16B of the tile;
    // their LDS writes land in the 256B pad (floats 4032..4095, never read).
    auto STAGE = [&](int q, size_t tile) {
        const char* srcP = (const char*)pred + tile * (size_t)TILE_BYTES;
        const char* srcG = (const char*)gt   + tile * (size_t)TILE_BYTES;
        #pragma unroll
        for (int c = 0; c < 4; ++c) {
            const int chunk = wave * 4 + c;
            int off = chunk * 1024 + lane * 16;
            if (off > TILE_BYTES - 16) off = TILE_BYTES - 16;
            __builtin_amdgcn_global_load_lds(
                (gvoid_t*)(srcP + off), (lvoid_t*)&lds[q][0][chunk * 256], 16, 0, 0);
            __builtin_amdgcn_global_load_lds(
                (gvoid_t*)(srcG + off), (lvoid_t*)&lds[q][1][chunk * 256], 16, 0, 0);
        }
    };

    float sum = 0.0f;

    STAGE(0, tile0);                               // prologue: tile 0 -> buf 0 (8 in flight)

    for (int t = 0; t < tiles_per_block; ++t) {
        if (t + 1 < tiles_per_block) {
            STAGE((t + 1) & 1, tile0 + t + 1);     // 8 more in flight (16 total)
            // retire tile t's 8 loads; keep tile t+1's 8 in flight across the barrier
            asm volatile("s_waitcnt vmcnt(8)\n\ts_barrier" ::: "memory");
        } else {
            asm volatile("s_waitcnt vmcnt(0)\n\ts_barrier" ::: "memory");
        }
        __builtin_amdgcn_sched_barrier(0);         // rule-18 insurance

        // ---- compute tile t: load 7 joints once, then 5 bones (static edges) ----
        {
            const float* SP = &lds[t & 1][0][smoff];
            const float* SG = &lds[t & 1][1][smoff];
            float px[7], py[7], pz[7], qx[7], qy[7], qz[7];
            #pragma unroll
            for (int k = 0; k < 7; ++k) {
                const int o = JT[k];
                px[k] = SP[o + 0]; py[k] = SP[o + 1]; pz[k] = SP[o + 2];
                qx[k] = SG[o + 0]; qy[k] = SG[o + 1]; qz[k] = SG[o + 2];
            }
            #pragma unroll
            for (int e = 0; e < 5; ++e) {
                const int a = EA[e], b = EB[e];
                float dx = px[a] - px[b];
                float dy = py[a] - py[b];
                float dz = pz[a] - pz[b];
                float pl = sqrtf(dx * dx + dy * dy + dz * dz);
                float ex = qx[a] - qx[b];
                float ey = qy[a] - qy[b];
                float ez = qz[a] - qz[b];
                float gl = sqrtf(ex * ex + ey * ey + ez * ez);
                sum += fabsf(pl - gl) / gl;
            }
        }

        // all waves done reading buf[t&1] before iter t+1 issues STAGE into it
        asm volatile("s_waitcnt lgkmcnt(0)\n\ts_barrier" ::: "memory");
    }

    // ---- wave64 shuffle reduction, then cross-wave via LDS ----
    #pragma unroll
    for (int off = 32; off > 0; off >>= 1)
        sum += __shfl_down(sum, off);

    if (lane == 0) wsum[wave] = sum;
    __syncthreads();
    if (tid == 0)
        atomicAdd(out, (wsum[0] + wsum[1] + wsum[2] + wsum[3]) * inv_count);
}

extern "C" void kernel_launch(void* const* d_in, const int* in_sizes, int n_in,
                              void* d_out, int out_size, void* d_ws, size_t ws_size,
                              hipStream_t stream) {
    const float* pred = (const float*)d_in[0];
    const float* gt   = (const float*)d_in[1];
    float* out = (float*)d_out;

    const int nsamples = in_sizes[0] / 63;            // 524288
    const int ntiles   = nsamples / 64;               // 8192
    const int tiles_per_block = ntiles / NBLOCKS;     // 16 (exact)

    const float inv_count = 1.0f / ((float)nsamples * 20.0f);

    // zero the single output float each call (replay-safe; capturable)
    hipMemsetAsync(out, 0, sizeof(float), stream);

    jll_kernel<<<NBLOCKS, 256, 0, stream>>>(pred, gt, out, inv_count, tiles_per_block);
}

// Round 8
// 47.589 us; speedup vs baseline: 1.1049x; 1.1049x over previous
//
#include <hip/hip_runtime.h>
#include <hip/hip_bf16.h>

// JointLengthLoss: mean over [B,20] of | ||pred_a-pred_b|| - ||gt_a-gt_b|| | / ||gt_a-gt_b||
// B = 524288, joints [B,21,3] f32.
//
// R7 = R5 staging (global_load_lds, double-buffered, counted vmcnt) +
//  wave-per-bone-group compute mapping: wave w computes bone group w for all
//  64 samples (lane = sample). Joint offsets are wave-uniform compile-time
//  immediates (template<G>, uniform branch on wave); LDS read banks are
//  (o - lane) mod 32 -> exactly 2 lanes/bank = conflict-free (m136).
//  Finalize reverted to two-kernel reduction (R6's atomicAdd regressed +3us).

#define TILE_BYTES   16128          // 64 samples * 63 floats * 4B
#define TILE_PAD_F   4096           // 16384 B per input per buffer (256B pad for clamped tail)
#define NBLOCKS      512

// 7-joint lists per bone group; edges are ALWAYS (0,1),(2,3),(3,4),(4,5),(5,6).
// g0: (3,2),(2,20),(20,8),(8,9),(9,10)       g1: (10,11),(20,4),(4,5),(5,6),(6,7)
// g2: (20,1),(1,0),(0,16),(16,17),(17,18)    g3: (18,19),(0,12),(12,13),(13,14),(14,15)
static constexpr int JT0[7] = {3,2,2,20,8,9,10};
static constexpr int JT1[7] = {10,11,20,4,5,6,7};
static constexpr int JT2[7] = {20,1,1,0,16,17,18};
static constexpr int JT3[7] = {18,19,0,12,13,14,15};
static constexpr int EA[5] = {0,2,3,4,5};
static constexpr int EB[5] = {1,3,4,5,6};

typedef __attribute__((address_space(1))) const void gvoid_t;
typedef __attribute__((address_space(3))) void lvoid_t;

template<int G>
__device__ __forceinline__ float bone_group(const float* __restrict__ SP,
                                            const float* __restrict__ SG) {
    float px[7], py[7], pz[7], qx[7], qy[7], qz[7];
    #pragma unroll
    for (int k = 0; k < 7; ++k) {
        const int o = 3 * ((G == 0) ? JT0[k] : (G == 1) ? JT1[k] : (G == 2) ? JT2[k] : JT3[k]);
        px[k] = SP[o + 0]; py[k] = SP[o + 1]; pz[k] = SP[o + 2];
        qx[k] = SG[o + 0]; qy[k] = SG[o + 1]; qz[k] = SG[o + 2];
    }
    float s = 0.0f;
    #pragma unroll
    for (int e = 0; e < 5; ++e) {
        const int a = EA[e], b = EB[e];
        float dx = px[a] - px[b];
        float dy = py[a] - py[b];
        float dz = pz[a] - pz[b];
        float pl = sqrtf(dx * dx + dy * dy + dz * dz);
        float ex = qx[a] - qx[b];
        float ey = qy[a] - qy[b];
        float ez = qz[a] - qz[b];
        float gl = sqrtf(ex * ex + ey * ey + ez * ez);
        s += fabsf(pl - gl) / gl;
    }
    return s;
}

__global__ __launch_bounds__(256)
void jll_kernel(const float* __restrict__ pred,
                const float* __restrict__ gt,
                float* __restrict__ partials,
                int tiles_per_block) {
    __shared__ __align__(16) float lds[2][2][TILE_PAD_F];   // [buf][input][floats] = 64 KiB
    __shared__ float wsum[4];

    const int tid  = threadIdx.x;
    const int wave = tid >> 6;
    const int lane = tid & 63;

    const size_t tile0 = (size_t)blockIdx.x * tiles_per_block;

    // STAGE: 8 global_load_lds per thread (4 chunks x {pred,gt}).
    // LDS dest: wave-uniform base + lane*16 (HW rule). Global src: per-lane.
    // Tail chunk 15: lanes >=48 clamp to the last valid 16B of the tile;
    // their LDS writes land in the 256B pad (floats 4032..4095, never read).
    auto STAGE = [&](int q, size_t tile) {
        const char* srcP = (const char*)pred + tile * (size_t)TILE_BYTES;
        const char* srcG = (const char*)gt   + tile * (size_t)TILE_BYTES;
        #pragma unroll
        for (int c = 0; c < 4; ++c) {
            const int chunk = wave * 4 + c;
            int off = chunk * 1024 + lane * 16;
            if (off > TILE_BYTES - 16) off = TILE_BYTES - 16;
            __builtin_amdgcn_global_load_lds(
                (gvoid_t*)(srcP + off), (lvoid_t*)&lds[q][0][chunk * 256], 16, 0, 0);
            __builtin_amdgcn_global_load_lds(
                (gvoid_t*)(srcG + off), (lvoid_t*)&lds[q][1][chunk * 256], 16, 0, 0);
        }
    };

    float sum = 0.0f;

    STAGE(0, tile0);                               // prologue: tile 0 -> buf 0 (8 in flight)

    for (int t = 0; t < tiles_per_block; ++t) {
        if (t + 1 < tiles_per_block) {
            STAGE((t + 1) & 1, tile0 + t + 1);     // 8 more in flight (16 total)
            // retire tile t's 8 loads; keep tile t+1's 8 in flight across the barrier
            asm volatile("s_waitcnt vmcnt(8)\n\ts_barrier" ::: "memory");
        } else {
            asm volatile("s_waitcnt vmcnt(0)\n\ts_barrier" ::: "memory");
        }
        __builtin_amdgcn_sched_barrier(0);         // rule-18 insurance

        // ---- compute tile t: wave w -> bone group w, lane -> sample ----
        {
            const float* SP = &lds[t & 1][0][lane * 63];
            const float* SG = &lds[t & 1][1][lane * 63];
            float ts;
            if      (wave == 0) ts = bone_group<0>(SP, SG);
            else if (wave == 1) ts = bone_group<1>(SP, SG);
            else if (wave == 2) ts = bone_group<2>(SP, SG);
            else                ts = bone_group<3>(SP, SG);
            sum += ts;
        }

        // all waves done reading buf[t&1] before iter t+1 issues STAGE into it
        asm volatile("s_waitcnt lgkmcnt(0)\n\ts_barrier" ::: "memory");
    }

    // ---- wave64 shuffle reduction, then cross-wave via LDS ----
    #pragma unroll
    for (int off = 32; off > 0; off >>= 1)
        sum += __shfl_down(sum, off);

    if (lane == 0) wsum[wave] = sum;
    __syncthreads();
    if (tid == 0)
        partials[blockIdx.x] = wsum[0] + wsum[1] + wsum[2] + wsum[3];
}

__global__ __launch_bounds__(256)
void jll_final_kernel(const float* __restrict__ partials, int nparts,
                      float* __restrict__ out, float inv_count) {
    const int tid = threadIdx.x;
    float sum = 0.0f;
    for (int i = tid; i < nparts; i += 256) sum += partials[i];

    #pragma unroll
    for (int off = 32; off > 0; off >>= 1)
        sum += __shfl_down(sum, off);

    __shared__ float wsum[4];
    const int lane = tid & 63;
    const int wid  = tid >> 6;
    if (lane == 0) wsum[wid] = sum;
    __syncthreads();
    if (tid == 0)
        out[0] = (wsum[0] + wsum[1] + wsum[2] + wsum[3]) * inv_count;
}

extern "C" void kernel_launch(void* const* d_in, const int* in_sizes, int n_in,
                              void* d_out, int out_size, void* d_ws, size_t ws_size,
                              hipStream_t stream) {
    const float* pred = (const float*)d_in[0];
    const float* gt   = (const float*)d_in[1];
    float* out = (float*)d_out;
    float* partials = (float*)d_ws;

    const int nsamples = in_sizes[0] / 63;            // 524288
    const int ntiles   = nsamples / 64;               // 8192
    const int tiles_per_block = ntiles / NBLOCKS;     // 16 (exact)

    jll_kernel<<<NBLOCKS, 256, 0, stream>>>(pred, gt, partials, tiles_per_block);

    const float inv_count = 1.0f / ((float)nsamples * 20.0f);
    jll_final_kernel<<<1, 256, 0, stream>>>(partials, NBLOCKS, out, inv_count);
}